// Round 1
// baseline (156.960 us; speedup 1.0000x reference)
//
#include <hip/hip_runtime.h>

// PointMassModel: X' = [v, a - g, c*(u - a)], RK4 x 8 substeps, h = DT/8.
// Linear constant-coefficient ODE => 8 RK4 substeps collapse to one affine map
//   s8 = P^8 s0 + S Q w,  w = E u + F g   (coefficients built host-side in double).
// Kernel is a pure streaming op: 176 MB logical per call.
//
// V2: latency-bound fix (prev: 53us @ 2.4 TB/s HBM, VALUBusy 5.6%, VGPR=20 ->
// staging loads serialized, full HBM latency exposed per 256-env tile).
// Each block now owns CHUNK=4 consecutive tiles, double-buffered LDS, and
// prefetches tile i+1 into named registers while computing/storing tile i.
// Barriers are raw s_barrier + lgkmcnt(0) ONLY -- no vmcnt drain, so the
// prefetch loads stay in flight across both barriers (a __syncthreads() would
// drain vmcnt and re-expose the latency).

#define THREADS 256
#define TILE 256          // envs per tile
#define CHUNK 4           // tiles per block (contiguous -> sequential DRAM)

struct Coeffs {
    float P00, P01, P02;
    float P10, P11, P12;
    float P20, P21, P22;
    float Ku0, Ku1, Ku2;   // R[:,2] * c   (u coefficient)
    float Kg0, Kg1, Kg2;   // -R[:,1]      (g coefficient)
};

// lgkm-only barrier: LDS writes visible, but outstanding global loads (vmcnt)
// are NOT drained. asm "memory" clobbers fence compiler reordering on both
// sides of the convergent s_barrier intrinsic.
__device__ __forceinline__ void barrier_lgkm() {
    asm volatile("s_waitcnt lgkmcnt(0)" ::: "memory");
    __builtin_amdgcn_s_barrier();
    asm volatile("" ::: "memory");
}

__device__ __forceinline__ void compute_env(const float* __restrict__ sx,
                                            const float* __restrict__ su,
                                            const Coeffs& cf, float r[9]) {
    #pragma unroll
    for (int k = 0; k < 3; ++k) {
        const float p = sx[k];
        const float v = sx[3 + k];
        const float a = sx[6 + k];
        const float u = su[k];
        const float g = (k == 2) ? -9.81f : 0.0f;
        r[k]     = cf.P00 * p + cf.P01 * v + cf.P02 * a + cf.Ku0 * u + cf.Kg0 * g;
        r[3 + k] = cf.P10 * p + cf.P11 * v + cf.P12 * a + cf.Ku1 * u + cf.Kg1 * g;
        r[6 + k] = cf.P20 * p + cf.P21 * v + cf.P22 * a + cf.Ku2 * u + cf.Kg2 * g;
    }
}

__global__ __launch_bounds__(THREADS)
void pointmass_kernel(const float* __restrict__ X0,
                      const float* __restrict__ U,
                      float* __restrict__ Out,
                      int envTotal, Coeffs cf) {
    // double-buffered tiles: 2*(9216 + 3072) = 24576 B -> 6 blocks/CU (LDS-bound)
    __shared__ float s_x[2][TILE * 9];
    __shared__ float s_u[2][TILE * 3];

    const int t = threadIdx.x;
    const int tileTotal = (envTotal + TILE - 1) / TILE;
    const int tb = blockIdx.x * CHUNK;
    if (tb >= tileTotal) return;
    const int te = min(tb + CHUNK, tileTotal);

    // fast path only when every tile in [tb, te) is full (true for N=2^21)
    const bool allFull = (te * TILE <= envTotal);

    if (allFull) {
        const float4* X4 = (const float4*)X0;
        const float4* U4 = (const float4*)U;
        float4* O4 = (float4*)Out;
        // per tile: X = 576 float4, U = 192 float4, Out = 576 float4.
        // thread t owns f4 slots {t, t+256, t+512 (t<64)} and u slot t (t<192).
        // NB: "if (t < 64)" / "if (t < 192)" are wave-uniform (wave=64).

        // ---- prologue: stage tile tb into buffer 0 ----
        {
            const size_t xb = (size_t)tb * 576;
            const size_t ub = (size_t)tb * 192;
            float4 a0 = X4[xb + t];
            float4 a1 = X4[xb + t + 256];
            float4 a2 = make_float4(0.f, 0.f, 0.f, 0.f);
            float4 b0 = make_float4(0.f, 0.f, 0.f, 0.f);
            if (t < 64)  a2 = X4[xb + t + 512];
            if (t < 192) b0 = U4[ub + t];
            ((float4*)s_x[0])[t]       = a0;   // compiler inserts vmcnt waits (data dep)
            ((float4*)s_x[0])[t + 256] = a1;
            if (t < 64)  ((float4*)s_x[0])[t + 512] = a2;
            if (t < 192) ((float4*)s_u[0])[t]       = b0;
        }
        barrier_lgkm();

        int cur = 0;
        for (int i = tb; i < te; ++i) {
            const bool haveNext = (i + 1 < te);    // block-uniform

            // (1) issue next tile's loads -> registers; stay in flight all iter
            float4 a0, a1;
            float4 a2 = make_float4(0.f, 0.f, 0.f, 0.f);
            float4 b0 = make_float4(0.f, 0.f, 0.f, 0.f);
            if (haveNext) {
                const size_t xb = (size_t)(i + 1) * 576;
                const size_t ub = (size_t)(i + 1) * 192;
                a0 = X4[xb + t];
                a1 = X4[xb + t + 256];
                if (t < 64)  a2 = X4[xb + t + 512];
                if (t < 192) b0 = U4[ub + t];
            }

            // (2) compute own env from LDS; write back in-place (own slots only)
            {
                float r[9];
                compute_env(s_x[cur] + t * 9, s_u[cur] + t * 3, cf, r);
                float* sxw = s_x[cur] + t * 9;
                #pragma unroll
                for (int q = 0; q < 9; ++q) sxw[q] = r[q];
            }
            barrier_lgkm();   // results visible; prefetch loads NOT drained

            // (3) cooperative coalesced store of tile i
            {
                const size_t ob = (size_t)i * 576;
                O4[ob + t]       = ((const float4*)s_x[cur])[t];
                O4[ob + t + 256] = ((const float4*)s_x[cur])[t + 256];
                if (t < 64) O4[ob + t + 512] = ((const float4*)s_x[cur])[t + 512];
            }

            // (4) land prefetch into the other buffer (vmcnt waits happen here,
            //     ~a full compute+store later than issue), then publish it
            if (haveNext) {
                const int nxt = cur ^ 1;
                ((float4*)s_x[nxt])[t]       = a0;
                ((float4*)s_x[nxt])[t + 256] = a1;
                if (t < 64)  ((float4*)s_x[nxt])[t + 512] = a2;
                if (t < 192) ((float4*)s_u[nxt])[t]       = b0;
                barrier_lgkm();
                cur = nxt;
            }
        }
    } else {
        // ---- generic fallback (partial tiles; unused for N=2^21 but safe) ----
        for (int i = tb; i < te; ++i) {
            const int base = i * TILE;
            const int n = min(TILE, envTotal - base);
            __syncthreads();   // protect s_x reuse across iterations
            for (int j = t; j < n * 9; j += THREADS)
                s_x[0][j] = X0[(size_t)base * 9 + j];
            for (int j = t; j < n * 3; j += THREADS)
                s_u[0][j] = U[(size_t)base * 3 + j];
            __syncthreads();
            if (t < n) {
                float r[9];
                compute_env(s_x[0] + t * 9, s_u[0] + t * 3, cf, r);
                #pragma unroll
                for (int q = 0; q < 9; ++q)
                    Out[((size_t)base + t) * 9 + q] = r[q];
            }
        }
    }
}

// ---------------- host-side coefficient computation ----------------
static void mat3_mul(const double A[3][3], const double B[3][3], double C[3][3]) {
    for (int i = 0; i < 3; ++i)
        for (int j = 0; j < 3; ++j) {
            double s = 0.0;
            for (int k = 0; k < 3; ++k) s += A[i][k] * B[k][j];
            C[i][j] = s;
        }
}
static void mat3_copy(const double A[3][3], double B[3][3]) {
    for (int i = 0; i < 3; ++i) for (int j = 0; j < 3; ++j) B[i][j] = A[i][j];
}

extern "C" void kernel_launch(void* const* d_in, const int* in_sizes, int n_in,
                              void* d_out, int out_size, void* d_ws, size_t ws_size,
                              hipStream_t stream) {
    const float* X0 = (const float*)d_in[0];
    const float* U  = (const float*)d_in[1];
    float* Out = (float*)d_out;
    const int envTotal = in_sizes[0] / 9;

    // --- build RK4 closed-form coefficients in double ---
    const double DT = 0.02;
    const double h = DT / 8.0;
    const double c = 0.5 / DT;                 // LMBDA / DT = 25
    double hA[3][3] = {{0, h, 0}, {0, 0, h}, {0, 0, -c * h}};

    double hA2[3][3], hA3[3][3], hA4[3][3];
    mat3_mul(hA, hA, hA2);
    mat3_mul(hA2, hA, hA3);
    mat3_mul(hA3, hA, hA4);

    double P[3][3], Q[3][3];
    for (int i = 0; i < 3; ++i)
        for (int j = 0; j < 3; ++j) {
            const double I = (i == j) ? 1.0 : 0.0;
            P[i][j] = I + hA[i][j] + hA2[i][j] / 2.0 + hA3[i][j] / 6.0 + hA4[i][j] / 24.0;
            Q[i][j] = h * (I + hA[i][j] / 2.0 + hA2[i][j] / 6.0 + hA3[i][j] / 24.0);
        }

    double P2[3][3], P4[3][3], P8[3][3];
    mat3_mul(P, P, P2);
    mat3_mul(P2, P2, P4);
    mat3_mul(P4, P4, P8);

    // S = I + P + ... + P^7 = (I+P)(I+P^2)(I+P^4)
    double IP[3][3], IP2[3][3], IP4[3][3], T[3][3], S[3][3], R[3][3];
    mat3_copy(P, IP);  mat3_copy(P2, IP2);  mat3_copy(P4, IP4);
    for (int i = 0; i < 3; ++i) { IP[i][i] += 1.0; IP2[i][i] += 1.0; IP4[i][i] += 1.0; }
    mat3_mul(IP, IP2, T);
    mat3_mul(T, IP4, S);
    mat3_mul(S, Q, R);

    Coeffs cf;
    cf.P00 = (float)P8[0][0]; cf.P01 = (float)P8[0][1]; cf.P02 = (float)P8[0][2];
    cf.P10 = (float)P8[1][0]; cf.P11 = (float)P8[1][1]; cf.P12 = (float)P8[1][2];
    cf.P20 = (float)P8[2][0]; cf.P21 = (float)P8[2][1]; cf.P22 = (float)P8[2][2];
    cf.Ku0 = (float)(R[0][2] * c); cf.Ku1 = (float)(R[1][2] * c); cf.Ku2 = (float)(R[2][2] * c);
    cf.Kg0 = (float)(-R[0][1]);    cf.Kg1 = (float)(-R[1][1]);    cf.Kg2 = (float)(-R[2][1]);

    const int tileTotal = (envTotal + TILE - 1) / TILE;
    const int blocks = (tileTotal + CHUNK - 1) / CHUNK;
    pointmass_kernel<<<blocks, THREADS, 0, stream>>>(X0, U, Out, envTotal, cf);
}

// Round 2
// 156.100 us; speedup vs baseline: 1.0055x; 1.0055x over previous
//
#include <hip/hip_runtime.h>

// PointMassModel: X' = [v, a - g, c*(u - a)], RK4 x 8 substeps, h = DT/8.
// Linear constant-coefficient ODE => 8 RK4 substeps collapse to one affine map
//   s8 = P^8 s0 + S Q w,  w = E u + F g   (coefficients built host-side in double).
// Pure streaming op: 176 MB logical per call.
//
// V3: wave-autonomous, BARRIER-FREE. v1 (simple, occ 66%) and v2 (reg-prefetch
// dbuf, occ 45%) both sit at ~53us / 2.38 TB/s HBM = ~half of copy ceiling,
// insensitive to occupancy and prefetch depth => block-wide barrier lockstep
// (burst-issue then block-wide stall) halves memory-pipe duty cycle.
// Fix: wave-tile = 64 envs, per-wave private LDS slice, NO s_barrier anywhere.
// All ordering is wave-local s_waitcnt from data deps; the prefetch-landing
// ds_write gets a counted vmcnt (stores stay in flight). Waves de-phase and
// issue continuously like a copy kernel.

#define THREADS 256
#define WAVES 4            // waves per block
#define WTILE 64           // envs per wave-tile
#define CHUNK 4            // contiguous tiles per wave
#define XF4 144            // float4 per wave-tile of X / Out (64 envs * 9 / 4)
#define UF4 48             // float4 per wave-tile of U        (64 envs * 3 / 4)

struct Coeffs {
    float P00, P01, P02;
    float P10, P11, P12;
    float P20, P21, P22;
    float Ku0, Ku1, Ku2;   // R[:,2] * c   (u coefficient)
    float Kg0, Kg1, Kg2;   // -R[:,1]      (g coefficient)
};

__device__ __forceinline__ void compute_env(const float* __restrict__ sx,
                                            const float* __restrict__ su,
                                            const Coeffs& cf, float r[9]) {
    #pragma unroll
    for (int k = 0; k < 3; ++k) {
        const float p = sx[k];
        const float v = sx[3 + k];
        const float a = sx[6 + k];
        const float u = su[k];
        const float g = (k == 2) ? -9.81f : 0.0f;
        r[k]     = cf.P00 * p + cf.P01 * v + cf.P02 * a + cf.Ku0 * u + cf.Kg0 * g;
        r[3 + k] = cf.P10 * p + cf.P11 * v + cf.P12 * a + cf.Ku1 * u + cf.Kg1 * g;
        r[6 + k] = cf.P20 * p + cf.P21 * v + cf.P22 * a + cf.Ku2 * u + cf.Kg2 * g;
    }
}

__global__ __launch_bounds__(THREADS)
void pointmass_kernel(const float* __restrict__ X0,
                      const float* __restrict__ U,
                      float* __restrict__ Out,
                      int envTotal, Coeffs cf) {
    // per-wave slice: 576 floats X/out + 192 floats U; double buffered.
    // 2 * 4 * 768 * 4B = 24576 B -> 6 blocks/CU (24 waves).
    __shared__ float lds[2][WAVES][768];

    const int t = threadIdx.x;
    const int w = t >> 6;          // wave id in block
    const int l = t & 63;          // lane
    const int fullTiles = envTotal / WTILE;
    const int tileBase = (blockIdx.x * WAVES + w) * CHUNK;
    const int te = min(tileBase + CHUNK, fullTiles);

    const float4* X4 = (const float4*)X0;
    const float4* U4 = (const float4*)U;
    float4* O4 = (float4*)Out;

    if (tileBase < te) {
        float* const xs0 = &lds[0][w][0];
        float* const us0 = &lds[0][w][576];
        float* const xs1 = &lds[1][w][0];
        float* const us1 = &lds[1][w][576];

        // ---- prologue: stage tile tileBase into buffer 0 (wave-local) ----
        {
            const size_t xb = (size_t)tileBase * XF4;
            const size_t ub = (size_t)tileBase * UF4;
            float4 a0 = X4[xb + l];
            float4 a1 = X4[xb + 64 + l];
            float4 a2 = make_float4(0.f, 0.f, 0.f, 0.f);
            float4 b0 = make_float4(0.f, 0.f, 0.f, 0.f);
            if (l < 16) a2 = X4[xb + 128 + l];
            if (l < 48) b0 = U4[ub + l];
            ((float4*)xs0)[l]      = a0;        // compiler: counted vmcnt waits
            ((float4*)xs0)[64 + l] = a1;
            if (l < 16) ((float4*)xs0)[128 + l] = a2;
            if (l < 48) ((float4*)us0)[l]       = b0;
        }

        int cur = 0;
        for (int i = tileBase; i < te; ++i) {
            float* const xs  = cur ? xs1 : xs0;
            float* const us  = cur ? us1 : us0;
            float* const xsN = cur ? xs0 : xs1;
            float* const usN = cur ? us0 : us1;
            const bool haveNext = (i + 1 < te);   // wave-uniform

            // (1) issue next tile's loads -> registers (in flight all iter)
            float4 a0, a1;
            float4 a2 = make_float4(0.f, 0.f, 0.f, 0.f);
            float4 b0 = make_float4(0.f, 0.f, 0.f, 0.f);
            if (haveNext) {
                const size_t xb = (size_t)(i + 1) * XF4;
                const size_t ub = (size_t)(i + 1) * UF4;
                a0 = X4[xb + l];
                a1 = X4[xb + 64 + l];
                if (l < 16) a2 = X4[xb + 128 + l];
                if (l < 48) b0 = U4[ub + l];
            }

            // (2) compute own env; lane-private LDS slots, no sync needed
            {
                float r[9];
                compute_env(xs + l * 9, us + l * 3, cf, r);
                float* sxw = xs + l * 9;
                #pragma unroll
                for (int q = 0; q < 9; ++q) sxw[q] = r[q];
            }

            // (3) coalesced float4 store of tile i (lgkm wait via data dep)
            {
                const size_t ob = (size_t)i * XF4;
                O4[ob + l]      = ((const float4*)xs)[l];
                O4[ob + 64 + l] = ((const float4*)xs)[64 + l];
                if (l < 16) O4[ob + 128 + l] = ((const float4*)xs)[128 + l];
            }

            // keep prefetch-landing below the stores: its vmcnt wait is then
            // counted (stores younger, stay in flight)
            __builtin_amdgcn_sched_barrier(0);

            // (4) land prefetch into the other buffer
            if (haveNext) {
                ((float4*)xsN)[l]      = a0;
                ((float4*)xsN)[64 + l] = a1;
                if (l < 16) ((float4*)xsN)[128 + l] = a2;
                if (l < 48) ((float4*)usN)[l]       = b0;
            }
            cur ^= 1;
        }
    }

    // ---- tail: remainder envs (none for N=2^21, but safe) ----
    const int rem0 = fullTiles * WTILE;
    if (rem0 < envTotal && blockIdx.x == gridDim.x - 1) {
        for (int e = rem0 + t; e < envTotal; e += THREADS) {
            float xr[9], ur[3], r[9];
            #pragma unroll
            for (int q = 0; q < 9; ++q) xr[q] = X0[(size_t)e * 9 + q];
            #pragma unroll
            for (int k = 0; k < 3; ++k) ur[k] = U[(size_t)e * 3 + k];
            compute_env(xr, ur, cf, r);
            #pragma unroll
            for (int q = 0; q < 9; ++q) Out[(size_t)e * 9 + q] = r[q];
        }
    }
}

// ---------------- host-side coefficient computation ----------------
static void mat3_mul(const double A[3][3], const double B[3][3], double C[3][3]) {
    for (int i = 0; i < 3; ++i)
        for (int j = 0; j < 3; ++j) {
            double s = 0.0;
            for (int k = 0; k < 3; ++k) s += A[i][k] * B[k][j];
            C[i][j] = s;
        }
}
static void mat3_copy(const double A[3][3], double B[3][3]) {
    for (int i = 0; i < 3; ++i) for (int j = 0; j < 3; ++j) B[i][j] = A[i][j];
}

extern "C" void kernel_launch(void* const* d_in, const int* in_sizes, int n_in,
                              void* d_out, int out_size, void* d_ws, size_t ws_size,
                              hipStream_t stream) {
    const float* X0 = (const float*)d_in[0];
    const float* U  = (const float*)d_in[1];
    float* Out = (float*)d_out;
    const int envTotal = in_sizes[0] / 9;

    // --- build RK4 closed-form coefficients in double ---
    const double DT = 0.02;
    const double h = DT / 8.0;
    const double c = 0.5 / DT;                 // LMBDA / DT = 25
    double hA[3][3] = {{0, h, 0}, {0, 0, h}, {0, 0, -c * h}};

    double hA2[3][3], hA3[3][3], hA4[3][3];
    mat3_mul(hA, hA, hA2);
    mat3_mul(hA2, hA, hA3);
    mat3_mul(hA3, hA, hA4);

    double P[3][3], Q[3][3];
    for (int i = 0; i < 3; ++i)
        for (int j = 0; j < 3; ++j) {
            const double I = (i == j) ? 1.0 : 0.0;
            P[i][j] = I + hA[i][j] + hA2[i][j] / 2.0 + hA3[i][j] / 6.0 + hA4[i][j] / 24.0;
            Q[i][j] = h * (I + hA[i][j] / 2.0 + hA2[i][j] / 6.0 + hA3[i][j] / 24.0);
        }

    double P2[3][3], P4[3][3], P8[3][3];
    mat3_mul(P, P, P2);
    mat3_mul(P2, P2, P4);
    mat3_mul(P4, P4, P8);

    // S = I + P + ... + P^7 = (I+P)(I+P^2)(I+P^4)
    double IP[3][3], IP2[3][3], IP4[3][3], T[3][3], S[3][3], R[3][3];
    mat3_copy(P, IP);  mat3_copy(P2, IP2);  mat3_copy(P4, IP4);
    for (int i = 0; i < 3; ++i) { IP[i][i] += 1.0; IP2[i][i] += 1.0; IP4[i][i] += 1.0; }
    mat3_mul(IP, IP2, T);
    mat3_mul(T, IP4, S);
    mat3_mul(S, Q, R);

    Coeffs cf;
    cf.P00 = (float)P8[0][0]; cf.P01 = (float)P8[0][1]; cf.P02 = (float)P8[0][2];
    cf.P10 = (float)P8[1][0]; cf.P11 = (float)P8[1][1]; cf.P12 = (float)P8[1][2];
    cf.P20 = (float)P8[2][0]; cf.P21 = (float)P8[2][1]; cf.P22 = (float)P8[2][2];
    cf.Ku0 = (float)(R[0][2] * c); cf.Ku1 = (float)(R[1][2] * c); cf.Ku2 = (float)(R[2][2] * c);
    cf.Kg0 = (float)(-R[0][1]);    cf.Kg1 = (float)(-R[1][1]);    cf.Kg2 = (float)(-R[2][1]);

    const int fullTiles = envTotal / WTILE;
    const int wavesNeeded = (fullTiles + CHUNK - 1) / CHUNK;
    int blocks = (wavesNeeded + WAVES - 1) / WAVES;
    if (blocks < 1) blocks = 1;
    pointmass_kernel<<<blocks, THREADS, 0, stream>>>(X0, U, Out, envTotal, cf);
}

// Round 3
// 153.532 us; speedup vs baseline: 1.0223x; 1.0167x over previous
//
#include <hip/hip_runtime.h>

// PointMassModel: X' = [v, a - g, c*(u - a)], RK4 x 8 substeps, h = DT/8.
// Linear constant-coefficient ODE => 8 RK4 substeps collapse to one affine map
//   s8 = P^8 s0 + S Q w,  w = E u + F g   (coefficients built host-side in double).
// Pure streaming op: 176 MB logical per call.
//
// V4: non-temporal output stores. Evidence: v1/v2/v3 (block-phased, dbuf
// prefetch, barrier-free wave-autonomous) ALL tie at 53-55us, 2.3-2.4 TB/s
// HBM, insensitive to occupancy (45-68%) and prefetch -> shared throughput
// cap, not latency. FETCH_SIZE = 49177.5 KB bit-identical across variants
// = exactly half the 98 MB logical input: steady-state MALL pollution --
// each iter's 75.5 MB output write-allocates in L2/L3 and evicts ~half the
// (otherwise fully L3-resident) input. Fix: 'nt' stores for Out (written
// once, never read) -> inputs stay L3-resident, reads served from Infinity
// Cache, HBM carries only the write stream.
// Predict: FETCH < 15 MB, dur 53 -> ~32-40us. If FETCH collapses but dur
// doesn't: L2/L3 request-rate ceiling -> roofline.

#define ENVS_PER_BLOCK 256
#define THREADS 256

typedef float f32x4 __attribute__((ext_vector_type(4)));

__device__ __forceinline__ void nt_store4(float* p, const float4 v) {
    f32x4 x;
    x[0] = v.x; x[1] = v.y; x[2] = v.z; x[3] = v.w;
    __builtin_nontemporal_store(x, (f32x4*)p);
}

struct Coeffs {
    float P00, P01, P02;
    float P10, P11, P12;
    float P20, P21, P22;
    float Ku0, Ku1, Ku2;   // R[:,2] * c   (u coefficient)
    float Kg0, Kg1, Kg2;   // -R[:,1]      (g coefficient)
};

__global__ __launch_bounds__(THREADS)
void pointmass_kernel(const float* __restrict__ X0,
                      const float* __restrict__ U,
                      float* __restrict__ Out,
                      int envTotal, Coeffs cf) {
    __shared__ float s_x[ENVS_PER_BLOCK * 9];   // 9216 B, reused for output
    __shared__ float s_u[ENVS_PER_BLOCK * 3];   // 3072 B

    const int t = threadIdx.x;
    const int blockBase = blockIdx.x * ENVS_PER_BLOCK;
    const int envsHere = min(ENVS_PER_BLOCK, envTotal - blockBase);

    if (envsHere == ENVS_PER_BLOCK) {
        // ---- fast path: fully coalesced float4 staging ----
        const float4* x4 = (const float4*)(X0 + (size_t)blockBase * 9);
        const float4* u4 = (const float4*)(U  + (size_t)blockBase * 3);
        float* o = Out + (size_t)blockBase * 9;

        #pragma unroll
        for (int j = t; j < ENVS_PER_BLOCK * 9 / 4; j += THREADS)   // 576 float4
            ((float4*)s_x)[j] = x4[j];
        if (t < ENVS_PER_BLOCK * 3 / 4)                              // 192 float4
            ((float4*)s_u)[t] = u4[t];
        __syncthreads();

        // per-thread env: stride-9-word LDS access = 2-way bank aliasing (free)
        float r[9];
        #pragma unroll
        for (int k = 0; k < 3; ++k) {
            const float p = s_x[t * 9 + k];
            const float v = s_x[t * 9 + 3 + k];
            const float a = s_x[t * 9 + 6 + k];
            const float u = s_u[t * 3 + k];
            const float g = (k == 2) ? -9.81f : 0.0f;
            r[k]     = cf.P00 * p + cf.P01 * v + cf.P02 * a + cf.Ku0 * u + cf.Kg0 * g;
            r[3 + k] = cf.P10 * p + cf.P11 * v + cf.P12 * a + cf.Ku1 * u + cf.Kg1 * g;
            r[6 + k] = cf.P20 * p + cf.P21 * v + cf.P22 * a + cf.Ku2 * u + cf.Kg2 * g;
        }
        // thread writes only its own 9 slots; sync before cooperative store
        #pragma unroll
        for (int i = 0; i < 9; ++i) s_x[t * 9 + i] = r[i];
        __syncthreads();

        // cooperative coalesced store, NON-TEMPORAL (no L2/MALL allocate)
        #pragma unroll
        for (int j = t; j < ENVS_PER_BLOCK * 9 / 4; j += THREADS) {
            const float4 v = ((const float4*)s_x)[j];
            nt_store4(o + j * 4, v);
        }
    } else {
        // ---- tail path (unused for N=2^21 but safe) ----
        for (int j = t; j < envsHere * 9; j += THREADS)
            s_x[j] = X0[(size_t)blockBase * 9 + j];
        for (int j = t; j < envsHere * 3; j += THREADS)
            s_u[j] = U[(size_t)blockBase * 3 + j];
        __syncthreads();
        if (t < envsHere) {
            float r[9];
            #pragma unroll
            for (int k = 0; k < 3; ++k) {
                const float p = s_x[t * 9 + k];
                const float v = s_x[t * 9 + 3 + k];
                const float a = s_x[t * 9 + 6 + k];
                const float u = s_u[t * 3 + k];
                const float g = (k == 2) ? -9.81f : 0.0f;
                r[k]     = cf.P00 * p + cf.P01 * v + cf.P02 * a + cf.Ku0 * u + cf.Kg0 * g;
                r[3 + k] = cf.P10 * p + cf.P11 * v + cf.P12 * a + cf.Ku1 * u + cf.Kg1 * g;
                r[6 + k] = cf.P20 * p + cf.P21 * v + cf.P22 * a + cf.Ku2 * u + cf.Kg2 * g;
            }
            #pragma unroll
            for (int i = 0; i < 9; ++i)
                Out[((size_t)blockBase + t) * 9 + i] = r[i];
        }
    }
}

// ---------------- host-side coefficient computation ----------------
static void mat3_mul(const double A[3][3], const double B[3][3], double C[3][3]) {
    for (int i = 0; i < 3; ++i)
        for (int j = 0; j < 3; ++j) {
            double s = 0.0;
            for (int k = 0; k < 3; ++k) s += A[i][k] * B[k][j];
            C[i][j] = s;
        }
}
static void mat3_copy(const double A[3][3], double B[3][3]) {
    for (int i = 0; i < 3; ++i) for (int j = 0; j < 3; ++j) B[i][j] = A[i][j];
}

extern "C" void kernel_launch(void* const* d_in, const int* in_sizes, int n_in,
                              void* d_out, int out_size, void* d_ws, size_t ws_size,
                              hipStream_t stream) {
    const float* X0 = (const float*)d_in[0];
    const float* U  = (const float*)d_in[1];
    float* Out = (float*)d_out;
    const int envTotal = in_sizes[0] / 9;

    // --- build RK4 closed-form coefficients in double ---
    const double DT = 0.02;
    const double h = DT / 8.0;
    const double c = 0.5 / DT;                 // LMBDA / DT = 25
    double hA[3][3] = {{0, h, 0}, {0, 0, h}, {0, 0, -c * h}};

    double hA2[3][3], hA3[3][3], hA4[3][3];
    mat3_mul(hA, hA, hA2);
    mat3_mul(hA2, hA, hA3);
    mat3_mul(hA3, hA, hA4);

    double P[3][3], Q[3][3];
    for (int i = 0; i < 3; ++i)
        for (int j = 0; j < 3; ++j) {
            const double I = (i == j) ? 1.0 : 0.0;
            P[i][j] = I + hA[i][j] + hA2[i][j] / 2.0 + hA3[i][j] / 6.0 + hA4[i][j] / 24.0;
            Q[i][j] = h * (I + hA[i][j] / 2.0 + hA2[i][j] / 6.0 + hA3[i][j] / 24.0);
        }

    double P2[3][3], P4[3][3], P8[3][3];
    mat3_mul(P, P, P2);
    mat3_mul(P2, P2, P4);
    mat3_mul(P4, P4, P8);

    // S = I + P + ... + P^7 = (I+P)(I+P^2)(I+P^4)
    double IP[3][3], IP2[3][3], IP4[3][3], T[3][3], S[3][3], R[3][3];
    mat3_copy(P, IP);  mat3_copy(P2, IP2);  mat3_copy(P4, IP4);
    for (int i = 0; i < 3; ++i) { IP[i][i] += 1.0; IP2[i][i] += 1.0; IP4[i][i] += 1.0; }
    mat3_mul(IP, IP2, T);
    mat3_mul(T, IP4, S);
    mat3_mul(S, Q, R);

    Coeffs cf;
    cf.P00 = (float)P8[0][0]; cf.P01 = (float)P8[0][1]; cf.P02 = (float)P8[0][2];
    cf.P10 = (float)P8[1][0]; cf.P11 = (float)P8[1][1]; cf.P12 = (float)P8[1][2];
    cf.P20 = (float)P8[2][0]; cf.P21 = (float)P8[2][1]; cf.P22 = (float)P8[2][2];
    cf.Ku0 = (float)(R[0][2] * c); cf.Ku1 = (float)(R[1][2] * c); cf.Ku2 = (float)(R[2][2] * c);
    cf.Kg0 = (float)(-R[0][1]);    cf.Kg1 = (float)(-R[1][1]);    cf.Kg2 = (float)(-R[2][1]);

    const int blocks = (envTotal + ENVS_PER_BLOCK - 1) / ENVS_PER_BLOCK;
    pointmass_kernel<<<blocks, THREADS, 0, stream>>>(X0, U, Out, envTotal, cf);
}

// Round 4
// 145.594 us; speedup vs baseline: 1.0781x; 1.0545x over previous
//
#include <hip/hip_runtime.h>

// PointMassModel: X' = [v, a - g, c*(u - a)], RK4 x 8 substeps, h = DT/8.
// Linear constant-coefficient ODE => 8 RK4 substeps collapse to one affine map
//   s8 = P^8 s0 + S Q w,  w = E u + F g   (coefficients built host-side in double).
// Pure streaming op: 172 MB real HBM per call.
//
// V5: nt-loads + deep read bursts. Counter forensics: FETCH_SIZE = 49177.5 KB
// bit-identical across 5 structural variants = EXACTLY half of input bytes ->
// gfx94x-formula artifact (gfx950 EA reads are 128B requests, counted as 64B).
// So real HBM = 172 MB/dispatch = 3.45 TB/s (55% of copy ceiling), no L3
// absorption. Eliminated: latency, lockstep, occupancy, LDS, VALU, pollution.
// Remaining read-path levers, both applied here:
//   (a) nt loads: input lines are used exactly once -- stop allocating them
//       in L2 (write stream is already nt since v4).
//   (b) 12 hand-batched nt-loads/thread into named regs (VGPR was 20 -> ~2
//       loads in flight; now ~12) => 9x longer uninterrupted per-wave read
//       bursts; 1024 envs/block => grid = 2048 blocks (G11 sweet spot).
// Predict: dur 49.7 -> 43-46us; FETCH/WRITE unchanged; VGPR ~64-72; occ ~37%.
// If +-2%: declare DRAM-mix structural ceiling (~3.5 TB/s) -> roofline.

#define ENVS_PER_BLOCK 1024
#define THREADS 256
#define XF4 (ENVS_PER_BLOCK * 9 / 4)   // 2304 float4 per block
#define UF4 (ENVS_PER_BLOCK * 3 / 4)   // 768 float4 per block

typedef float f32x4 __attribute__((ext_vector_type(4)));

__device__ __forceinline__ f32x4 nt_load4(const float* p) {
    return __builtin_nontemporal_load((const f32x4*)p);
}
__device__ __forceinline__ void nt_store4(float* p, const f32x4 v) {
    __builtin_nontemporal_store(v, (f32x4*)p);
}

struct Coeffs {
    float P00, P01, P02;
    float P10, P11, P12;
    float P20, P21, P22;
    float Ku0, Ku1, Ku2;   // R[:,2] * c   (u coefficient)
    float Kg0, Kg1, Kg2;   // -R[:,1]      (g coefficient)
};

__device__ __forceinline__ void compute_env(const float* __restrict__ sx,
                                            const float* __restrict__ su,
                                            const Coeffs& cf, float r[9]) {
    #pragma unroll
    for (int k = 0; k < 3; ++k) {
        const float p = sx[k];
        const float v = sx[3 + k];
        const float a = sx[6 + k];
        const float u = su[k];
        const float g = (k == 2) ? -9.81f : 0.0f;
        r[k]     = cf.P00 * p + cf.P01 * v + cf.P02 * a + cf.Ku0 * u + cf.Kg0 * g;
        r[3 + k] = cf.P10 * p + cf.P11 * v + cf.P12 * a + cf.Ku1 * u + cf.Kg1 * g;
        r[6 + k] = cf.P20 * p + cf.P21 * v + cf.P22 * a + cf.Ku2 * u + cf.Kg2 * g;
    }
}

__global__ __launch_bounds__(THREADS)
void pointmass_kernel(const float* __restrict__ X0,
                      const float* __restrict__ U,
                      float* __restrict__ Out,
                      int envTotal, Coeffs cf) {
    // 1024 envs: 36 KiB X/out + 12 KiB U = 48 KiB -> 3 blocks/CU (LDS-bound)
    __shared__ float s_x[ENVS_PER_BLOCK * 9];
    __shared__ float s_u[ENVS_PER_BLOCK * 3];

    const int t = threadIdx.x;
    const int blockBase = blockIdx.x * ENVS_PER_BLOCK;
    const int envsHere = min(ENVS_PER_BLOCK, envTotal - blockBase);

    if (envsHere == ENVS_PER_BLOCK) {
        const float* xg = X0 + (size_t)blockBase * 9;
        const float* ug = U  + (size_t)blockBase * 3;
        float* og = Out + (size_t)blockBase * 9;

        // ---- stage: 9+3 nt-loads per thread, hand-batched (deep MLP) ----
        f32x4 xr[9], ur[3];
        #pragma unroll
        for (int q = 0; q < 9; ++q) xr[q] = nt_load4(xg + (q * THREADS + t) * 4);
        #pragma unroll
        for (int q = 0; q < 3; ++q) ur[q] = nt_load4(ug + (q * THREADS + t) * 4);
        #pragma unroll
        for (int q = 0; q < 9; ++q) ((f32x4*)s_x)[q * THREADS + t] = xr[q];
        #pragma unroll
        for (int q = 0; q < 3; ++q) ((f32x4*)s_u)[q * THREADS + t] = ur[q];
        __syncthreads();

        // ---- compute: 4 envs/thread, env = t + ee*256 (stride-9 words
        //      across lanes = all 32 banks, 2-way alias = free) ----
        #pragma unroll
        for (int ee = 0; ee < 4; ++ee) {
            const int e = t + ee * THREADS;
            float r[9];
            compute_env(s_x + e * 9, s_u + e * 3, cf, r);
            #pragma unroll
            for (int i = 0; i < 9; ++i) s_x[e * 9 + i] = r[i];
        }
        __syncthreads();

        // ---- store: 9 nt float4 per thread, coalesced sequential ----
        #pragma unroll
        for (int q = 0; q < 9; ++q) {
            const f32x4 v = ((const f32x4*)s_x)[q * THREADS + t];
            nt_store4(og + (q * THREADS + t) * 4, v);
        }
    } else {
        // ---- tail path (unused for N=2^21 but safe) ----
        for (int j = t; j < envsHere * 9; j += THREADS)
            s_x[j] = X0[(size_t)blockBase * 9 + j];
        for (int j = t; j < envsHere * 3; j += THREADS)
            s_u[j] = U[(size_t)blockBase * 3 + j];
        __syncthreads();
        for (int e = t; e < envsHere; e += THREADS) {
            float r[9];
            compute_env(s_x + e * 9, s_u + e * 3, cf, r);
            #pragma unroll
            for (int i = 0; i < 9; ++i)
                Out[((size_t)blockBase + e) * 9 + i] = r[i];
        }
    }
}

// ---------------- host-side coefficient computation ----------------
static void mat3_mul(const double A[3][3], const double B[3][3], double C[3][3]) {
    for (int i = 0; i < 3; ++i)
        for (int j = 0; j < 3; ++j) {
            double s = 0.0;
            for (int k = 0; k < 3; ++k) s += A[i][k] * B[k][j];
            C[i][j] = s;
        }
}
static void mat3_copy(const double A[3][3], double B[3][3]) {
    for (int i = 0; i < 3; ++i) for (int j = 0; j < 3; ++j) B[i][j] = A[i][j];
}

extern "C" void kernel_launch(void* const* d_in, const int* in_sizes, int n_in,
                              void* d_out, int out_size, void* d_ws, size_t ws_size,
                              hipStream_t stream) {
    const float* X0 = (const float*)d_in[0];
    const float* U  = (const float*)d_in[1];
    float* Out = (float*)d_out;
    const int envTotal = in_sizes[0] / 9;

    // --- build RK4 closed-form coefficients in double ---
    const double DT = 0.02;
    const double h = DT / 8.0;
    const double c = 0.5 / DT;                 // LMBDA / DT = 25
    double hA[3][3] = {{0, h, 0}, {0, 0, h}, {0, 0, -c * h}};

    double hA2[3][3], hA3[3][3], hA4[3][3];
    mat3_mul(hA, hA, hA2);
    mat3_mul(hA2, hA, hA3);
    mat3_mul(hA3, hA, hA4);

    double P[3][3], Q[3][3];
    for (int i = 0; i < 3; ++i)
        for (int j = 0; j < 3; ++j) {
            const double I = (i == j) ? 1.0 : 0.0;
            P[i][j] = I + hA[i][j] + hA2[i][j] / 2.0 + hA3[i][j] / 6.0 + hA4[i][j] / 24.0;
            Q[i][j] = h * (I + hA[i][j] / 2.0 + hA2[i][j] / 6.0 + hA3[i][j] / 24.0);
        }

    double P2[3][3], P4[3][3], P8[3][3];
    mat3_mul(P, P, P2);
    mat3_mul(P2, P2, P4);
    mat3_mul(P4, P4, P8);

    // S = I + P + ... + P^7 = (I+P)(I+P^2)(I+P^4)
    double IP[3][3], IP2[3][3], IP4[3][3], T[3][3], S[3][3], R[3][3];
    mat3_copy(P, IP);  mat3_copy(P2, IP2);  mat3_copy(P4, IP4);
    for (int i = 0; i < 3; ++i) { IP[i][i] += 1.0; IP2[i][i] += 1.0; IP4[i][i] += 1.0; }
    mat3_mul(IP, IP2, T);
    mat3_mul(T, IP4, S);
    mat3_mul(S, Q, R);

    Coeffs cf;
    cf.P00 = (float)P8[0][0]; cf.P01 = (float)P8[0][1]; cf.P02 = (float)P8[0][2];
    cf.P10 = (float)P8[1][0]; cf.P11 = (float)P8[1][1]; cf.P12 = (float)P8[1][2];
    cf.P20 = (float)P8[2][0]; cf.P21 = (float)P8[2][1]; cf.P22 = (float)P8[2][2];
    cf.Ku0 = (float)(R[0][2] * c); cf.Ku1 = (float)(R[1][2] * c); cf.Ku2 = (float)(R[2][2] * c);
    cf.Kg0 = (float)(-R[0][1]);    cf.Kg1 = (float)(-R[1][1]);    cf.Kg2 = (float)(-R[2][1]);

    const int blocks = (envTotal + ENVS_PER_BLOCK - 1) / ENVS_PER_BLOCK;
    pointmass_kernel<<<blocks, THREADS, 0, stream>>>(X0, U, Out, envTotal, cf);
}